// Round 2
// baseline (376.235 us; speedup 1.0000x reference)
//
#include <hip/hip_runtime.h>
#include <hip/hip_bf16.h>
#include <stdint.h>

typedef __attribute__((ext_vector_type(4))) float f32x4;
typedef __attribute__((ext_vector_type(16))) float f32x16;
typedef __attribute__((ext_vector_type(8))) short short8;
typedef __attribute__((ext_vector_type(2))) int int2v;

#define DEV static __device__ __forceinline__

DEV unsigned short f2bf(float f) {
  unsigned u = __float_as_uint(f);
  u += 0x7fffu + ((u >> 16) & 1u);
  return (unsigned short)(u >> 16);
}

DEV uint32_t cvtpk(float a, float b) {  // {lo: bf16(a), hi: bf16(b)}
  uint32_t r;
  asm("v_cvt_pk_bf16_f32 %0, %1, %2" : "=v"(r) : "v"(a), "v"(b));
  return r;
}

// v_permlane32_swap_b32: r.x = {a[0:31], b[0:31] in hi lanes}, r.y = {a[32:63] in lo lanes, b[32:63]}
DEV int2v pl32(int a, int b) {
  return __builtin_amdgcn_permlane32_swap(a, b, false, false);
}

typedef const __attribute__((address_space(1))) void* gas_ptr;
typedef __attribute__((address_space(3))) void* las_ptr;

DEV void gload_lds16(const void* g, void* l) {
  __builtin_amdgcn_global_load_lds((gas_ptr)g, (las_ptr)l, 16, 0, 0);
}

// ---------------- f32 -> bf16 elementwise convert, all 6 tensors in one launch ----------------
struct CvtArgs {
  const float* in[6];
  unsigned short* out[6];
};

__global__ __launch_bounds__(256) void cvt_kernel(CvtArgs a, int n4) {
  const float* __restrict__ in = a.in[blockIdx.y];
  unsigned short* __restrict__ out = a.out[blockIdx.y];
  int idx = blockIdx.x * blockDim.x + threadIdx.x;
  int stride = gridDim.x * blockDim.x;
  for (int i = idx; i < n4; i += stride) {
    float4 v = reinterpret_cast<const float4*>(in)[i];
    ushort4 o;
    o.x = f2bf(v.x); o.y = f2bf(v.y); o.z = f2bf(v.z); o.w = f2bf(v.w);
    reinterpret_cast<ushort4*>(out)[i] = o;
  }
}

// ------------- weight transpose+convert: src f32 [1024 k][1024 n] -> dst bf16 [n][k], 7 in one ----
struct TcvtArgs {
  const float* src[7];
  unsigned short* dst[7];
  int stride[7];
  int koff[7];
};

__global__ __launch_bounds__(256) void tcvt_kernel(TcvtArgs a) {
  const int which = blockIdx.z;
  const float* __restrict__ src = a.src[which];
  unsigned short* __restrict__ dst = a.dst[which];
  const int dstStride = a.stride[which], kOff = a.koff[which];
  __shared__ float tile[32][33];
  int tx = threadIdx.x & 31;   // 0..31
  int ty = threadIdx.x >> 5;   // 0..7
  int n0 = blockIdx.x * 32;
  int k0 = blockIdx.y * 32;
#pragma unroll
  for (int i = 0; i < 4; i++)
    tile[ty + 8 * i][tx] = src[(size_t)(k0 + ty + 8 * i) * 1024 + n0 + tx];
  __syncthreads();
#pragma unroll
  for (int i = 0; i < 4; i++) {
    int n = n0 + ty + 8 * i;
    dst[(size_t)n * dstStride + kOff + k0 + tx] = f2bf(tile[tx][ty + 8 * i]);
  }
}

// ---------------- merged Q/K/V projection GEMM, 256x256 8-wave, region-recycled pipeline -------
// C[8192 x 1024] = concat_k(A1,A2) @ W  (W transposed [n][k], Ktot=2048, ksplit=1024)
// 512 thr / 8 waves (2M x 4N), per-wave 128x64 output, BK=64, LDS 128KB (2 tile buffers).
// T2 swizzle: phys_byte = row*128 + (colbyte ^ ((row&7)<<4)); staged via linear LDS dest +
// inverse-swizzled GLOBAL source (involution; rule #21).
// Deep pipeline (7-phase load cover): during tile t we stage tile t+2 back into the buffer
// being consumed (regions die phase-by-phase):
//   ph0: reads B(all)+A0(cur);       stage g0 = A3(t+1) -> other buf   [1 gload]
//   ph1: reads A1(cur);              stage g1 = B0,B1,A0(t+2) -> cur   [3 gloads]
//   ph2: reads A2(cur);              stage g2 = B2,B3,A1(t+2) -> cur   [3 gloads]
//   ph3: reads A3(cur);              stage g3 = A2(t+2) -> cur         [1 gload]
// Counted waits (exact FIFO arithmetic): end-ph0 none, end-ph1 vmcnt(12), end-ph2 vmcnt(14),
// end-ph3 vmcnt(9).  Every load has 6-7 phases (~1600 cy) of cover >> HBM latency (~900 cy).
struct G3Args {
  const unsigned short* A1[3];
  const unsigned short* A2[3];
  const unsigned short* WT[3];
  unsigned short* out[3];
};

__global__ __launch_bounds__(512, 2) void gemm3_kernel(G3Args g) {
  __shared__ unsigned short As[2][256 * 64];
  __shared__ unsigned short Bs[2][256 * 64];
  const int orig = blockIdx.x;
  const int swz = (orig & 7) * 48 + (orig >> 3);  // 384 blocks, bijective XCD chunk
  const int which = swz >> 7;                      // 128 blocks per GEMM
  const int bid = swz & 127;
  const unsigned short* __restrict__ A1 = g.A1[which];
  const unsigned short* __restrict__ A2 = g.A2[which];
  const unsigned short* __restrict__ WT = g.WT[which];
  unsigned short* __restrict__ outp = g.out[which];

  const int tid = threadIdx.x;
  const int lane = tid & 63;
  const int w = tid >> 6;                 // 0..7
  const int mt = bid >> 2, nt = bid & 3;
  const int m0 = mt * 256, n0 = nt * 256;
  const int wr = w >> 2, wc = w & 3;      // 2 x 4 wave grid

  // ---- staging geometry: each wave stages 8 rows x 128B per gload round ----
  const int lr = lane >> 3;                        // row within 8-row stripe
  const int lcsw = (((lane & 7) ^ lr) << 3);       // inverse-swizzled col (ushorts)
  const int aW = (w < 4) ? (w * 8) : (128 + (w - 4) * 8);  // A round r: rows aW + r*32
  const int bW = w * 8;                                     // B round r: rows bW + r*64

  // ---- fragment ds_read addressing (swizzled, ushort indices) ----
  const int la = lane & 15;
  const int szb = (lane & 7) << 4;                 // swizzle bytes
  int cF[2];
#pragma unroll
  for (int ks = 0; ks < 2; ks++)
    cF[ks] = (((ks << 6) + ((lane >> 4) << 4)) ^ szb) >> 1;
  const int arA = (wr * 128 + la) * 64;            // + mf*1024 + cF[ks]
  const int brB = (wc * 64 + la) * 64;             // + nf*1024 + cF[ks]

  f32x4 zero4 = {0.f, 0.f, 0.f, 0.f};
  f32x4 acc[8][4];
#pragma unroll
  for (int mf = 0; mf < 8; mf++)
#pragma unroll
    for (int nf = 0; nf < 4; nf++) acc[mf][nf] = zero4;

  short8 bf[4][2];

  auto STAGE_B1 = [&](int buf, int kk, int r) {  // one B round = rows [r*64,(r+1)*64)
    gload_lds16(WT + (size_t)(n0 + bW + r * 64 + lr) * 2048 + kk + lcsw,
                &Bs[buf][(bW + r * 64) * 64 + lane * 8]);
  };
  auto STAGE_A = [&](int buf, int kk, int r) {   // one A round = rows [r*32,..)+[128+r*32,..)
    const unsigned short* Ab = (kk < 1024) ? A1 : A2;
    const int ka = kk & 1023;
    gload_lds16(Ab + (size_t)(m0 + aW + r * 32 + lr) * 1024 + ka + lcsw,
                &As[buf][(aW + r * 32) * 64 + lane * 8]);
  };
  auto READ_B = [&](int buf) {
#pragma unroll
    for (int nf = 0; nf < 4; nf++)
#pragma unroll
      for (int ks = 0; ks < 2; ks++)
        bf[nf][ks] = *reinterpret_cast<const short8*>(&Bs[buf][brB + nf * 1024 + cF[ks]]);
  };

#define READ_A(buf, p, af)                                                               \
  _Pragma("unroll") for (int mi = 0; mi < 2; mi++)                                       \
      _Pragma("unroll") for (int ks = 0; ks < 2; ks++)                                   \
          af[mi][ks] = *reinterpret_cast<const short8*>(                                 \
              &As[buf][arA + (2 * (p) + mi) * 1024 + cF[ks]]);

#define MFMA_P(p, af)                                                                    \
  _Pragma("unroll") for (int mi = 0; mi < 2; mi++)                                       \
      _Pragma("unroll") for (int nf = 0; nf < 4; nf++)                                   \
          _Pragma("unroll") for (int ks = 0; ks < 2; ks++)                               \
              acc[2 * (p) + mi][nf] = __builtin_amdgcn_mfma_f32_16x16x32_bf16(           \
                  af[mi][ks], bf[nf][ks], acc[2 * (p) + mi][nf], 0, 0, 0);

  // ---- prologue: queue order mimics steady-state groups g1(-2)..g3(-1), 15 gloads ----
  STAGE_B1(0, 0, 0); STAGE_B1(0, 0, 1); STAGE_A(0, 0, 0);     // g1(-2)
  STAGE_B1(0, 0, 2); STAGE_B1(0, 0, 3); STAGE_A(0, 0, 1);     // g2(-2)
  STAGE_A(0, 0, 2);                                           // g3(-2)
  STAGE_A(0, 0, 3);                                           // g0(-1)
  STAGE_B1(1, 64, 0); STAGE_B1(1, 64, 1); STAGE_A(1, 64, 0);  // g1(-1)
  STAGE_B1(1, 64, 2); STAGE_B1(1, 64, 3); STAGE_A(1, 64, 1);  // g2(-1)
  STAGE_A(1, 64, 2);                                          // g3(-1)
  asm volatile("s_waitcnt vmcnt(9)" ::: "memory");  // completes g1(-2),g2(-2): B+A0,A1(t0)
  __builtin_amdgcn_s_barrier();
  __builtin_amdgcn_sched_barrier(0);

  for (int kt = 0; kt < 30; kt++) {
    const int cur = kt & 1;
    const int nxt = cur ^ 1;
    const int kk1 = (kt + 1) << 6;
    const int kk2 = (kt + 2) << 6;
    // ---------------- phase 0 ----------------
    {
      READ_B(cur);
      short8 af[2][2];
      READ_A(cur, 0, af);
      STAGE_A(nxt, kk1, 3);  // g0: A3(t+1) (region dead since t-1 ph3)
      asm volatile("s_waitcnt lgkmcnt(0)" ::: "memory");
      __builtin_amdgcn_sched_barrier(0);
      __builtin_amdgcn_s_setprio(1);
      MFMA_P(0, af);
      __builtin_amdgcn_s_setprio(0);
      __builtin_amdgcn_sched_barrier(0);
      __builtin_amdgcn_s_barrier();  // no vmcnt: ph1's need certified one tile ago
      __builtin_amdgcn_sched_barrier(0);
    }
    // ---------------- phase 1 ----------------
    {
      short8 af[2][2];
      READ_A(cur, 1, af);
      STAGE_B1(cur, kk2, 0); STAGE_B1(cur, kk2, 1); STAGE_A(cur, kk2, 0);  // g1 -> cur
      asm volatile("s_waitcnt lgkmcnt(0)" ::: "memory");
      __builtin_amdgcn_sched_barrier(0);
      __builtin_amdgcn_s_setprio(1);
      MFMA_P(1, af);
      __builtin_amdgcn_s_setprio(0);
      __builtin_amdgcn_sched_barrier(0);
      asm volatile("s_waitcnt vmcnt(12)" ::: "memory");  // certifies A2(cur) for ph2
      __builtin_amdgcn_s_barrier();
      __builtin_amdgcn_sched_barrier(0);
    }
    // ---------------- phase 2 ----------------
    {
      short8 af[2][2];
      READ_A(cur, 2, af);
      STAGE_B1(cur, kk2, 2); STAGE_B1(cur, kk2, 3); STAGE_A(cur, kk2, 1);  // g2 -> cur
      asm volatile("s_waitcnt lgkmcnt(0)" ::: "memory");
      __builtin_amdgcn_sched_barrier(0);
      __builtin_amdgcn_s_setprio(1);
      MFMA_P(2, af);
      __builtin_amdgcn_s_setprio(0);
      __builtin_amdgcn_sched_barrier(0);
      asm volatile("s_waitcnt vmcnt(14)" ::: "memory");  // certifies A3(cur) for ph3
      __builtin_amdgcn_s_barrier();
      __builtin_amdgcn_sched_barrier(0);
    }
    // ---------------- phase 3 ----------------
    {
      short8 af[2][2];
      READ_A(cur, 3, af);
      STAGE_A(cur, kk2, 2);  // g3 -> cur
      asm volatile("s_waitcnt lgkmcnt(0)" ::: "memory");
      __builtin_amdgcn_sched_barrier(0);
      __builtin_amdgcn_s_setprio(1);
      MFMA_P(3, af);
      __builtin_amdgcn_s_setprio(0);
      __builtin_amdgcn_sched_barrier(0);
      asm volatile("s_waitcnt vmcnt(9)" ::: "memory");  // certifies B+A0(next) for ph0
      __builtin_amdgcn_s_barrier();
      __builtin_amdgcn_sched_barrier(0);
    }
  }

  // ---- epilogue: tiles 30 (buf0) and 31 (buf1); everything already staged ----
  {
    READ_B(0);
    short8 af[2][2];
    READ_A(0, 0, af);
    STAGE_A(1, 1984, 3);  // A3(t31) -> buf1 (region dead since t30... t29 ph3)
    asm volatile("s_waitcnt lgkmcnt(0)" ::: "memory");
    __builtin_amdgcn_sched_barrier(0);
    __builtin_amdgcn_s_setprio(1);
    MFMA_P(0, af);
    __builtin_amdgcn_s_setprio(0);
    __builtin_amdgcn_sched_barrier(0);
    asm volatile("s_waitcnt vmcnt(0)" ::: "memory");  // drain: all data resident in LDS
    __builtin_amdgcn_s_barrier();
    __builtin_amdgcn_sched_barrier(0);
#pragma unroll
    for (int p = 1; p < 4; p++) {
      short8 af2[2][2];
      READ_A(0, p, af2);
      asm volatile("s_waitcnt lgkmcnt(0)" ::: "memory");
      __builtin_amdgcn_sched_barrier(0);
      MFMA_P(p, af2);
    }
    READ_B(1);
    short8 af3[2][2];
    READ_A(1, 0, af3);
    asm volatile("s_waitcnt lgkmcnt(0)" ::: "memory");
    __builtin_amdgcn_sched_barrier(0);
    MFMA_P(0, af3);
#pragma unroll
    for (int p = 1; p < 4; p++) {
      short8 af4[2][2];
      READ_A(1, p, af4);
      asm volatile("s_waitcnt lgkmcnt(0)" ::: "memory");
      __builtin_amdgcn_sched_barrier(0);
      MFMA_P(p, af4);
    }
  }

  // epilogue: D layout col = lane&15, row = (lane>>4)*4 + reg
#pragma unroll
  for (int mf = 0; mf < 8; mf++) {
#pragma unroll
    for (int nf = 0; nf < 4; nf++) {
      const int col = n0 + wc * 64 + nf * 16 + (lane & 15);
      const int rbase = m0 + wr * 128 + mf * 16 + ((lane >> 4) << 2);
      const int h = col >> 6, d = col & 63;
      if (which < 2) {
#pragma unroll
        for (int r = 0; r < 4; r++) {
          const int m = rbase + r;
          const int b = m >> 11, l = m & 2047;
          outp[((size_t)((b * 16 + h) * 2048 + l)) * 64 + d] = f2bf(acc[mf][nf][r]);
        }
      } else {
        // V tiled: [bh][l/32][d][l%32], tile = 64x32 = 4KB contiguous
        const int m = rbase;
        const int b = m >> 11, l = m & 2047;
        const int bh = b * 16 + h;
        ushort4 o;
        o.x = f2bf(acc[mf][nf][0]);
        o.y = f2bf(acc[mf][nf][1]);
        o.z = f2bf(acc[mf][nf][2]);
        o.w = f2bf(acc[mf][nf][3]);
        *reinterpret_cast<ushort4*>(
            outp + (size_t)(bh * 64 + (l >> 5)) * 2048 + d * 32 + (l & 31)) = o;
      }
    }
  }
}

// ---------------- fc GEMM: C[8192 x 1024] = A @ W, f32 out ----------------
__global__ __launch_bounds__(256) void gemmfc_kernel(const unsigned short* __restrict__ A1,
                                                     const unsigned short* __restrict__ WT,
                                                     float* __restrict__ outp) {
  __shared__ unsigned short As[128 * 32];
  __shared__ unsigned short Bs[128 * 32];
  const int orig = blockIdx.x;
  const int bid = (orig & 7) * 64 + (orig >> 3);  // 512 blocks, bijective XCD chunk
  const int tid = threadIdx.x;
  const int lane = tid & 63;
  const int w = tid >> 6;
  const int mt = bid >> 3, nt = bid & 7;
  const int m0 = mt * 128, n0 = nt * 128;

  const int srow = (w << 4) + (lane >> 2);
  const int scol = (lane & 3) << 3;

  f32x4 zero4 = {0.f, 0.f, 0.f, 0.f};
  f32x4 acc[4][4];
#pragma unroll
  for (int mi = 0; mi < 4; mi++)
#pragma unroll
    for (int ni = 0; ni < 4; ni++) acc[mi][ni] = zero4;

  const int wr = w >> 1, wc = w & 1;
  const int arow = (wr << 6) + (lane & 15);
  const int brow = (wc << 6) + (lane & 15);
  const int kcol = (lane >> 4) << 3;

  for (int kt = 0; kt < 32; kt++) {
    const int kk = kt << 5;
#pragma unroll
    for (int p = 0; p < 2; p++) {
      const unsigned short* gp = A1 + (size_t)(m0 + p * 64 + srow) * 1024 + kk + scol;
      gload_lds16(gp, &As[(p * 64 + srow) * 32 + scol]);
    }
#pragma unroll
    for (int p = 0; p < 2; p++) {
      const unsigned short* gp = WT + (size_t)(n0 + p * 64 + srow) * 1024 + kk + scol;
      gload_lds16(gp, &Bs[(p * 64 + srow) * 32 + scol]);
    }
    __syncthreads();

    short8 av[4], bv[4];
#pragma unroll
    for (int mi = 0; mi < 4; mi++)
      av[mi] = *reinterpret_cast<const short8*>(&As[(arow + mi * 16) * 32 + kcol]);
#pragma unroll
    for (int ni = 0; ni < 4; ni++)
      bv[ni] = *reinterpret_cast<const short8*>(&Bs[(brow + ni * 16) * 32 + kcol]);
#pragma unroll
    for (int mi = 0; mi < 4; mi++)
#pragma unroll
      for (int ni = 0; ni < 4; ni++)
        acc[mi][ni] = __builtin_amdgcn_mfma_f32_16x16x32_bf16(av[mi], bv[ni], acc[mi][ni], 0, 0, 0);
    __syncthreads();
  }

#pragma unroll
  for (int mi = 0; mi < 4; mi++) {
#pragma unroll
    for (int ni = 0; ni < 4; ni++) {
      const int col = n0 + (wc << 6) + ni * 16 + (lane & 15);
      const int rbase = m0 + (wr << 6) + mi * 16 + ((lane >> 4) << 2);
#pragma unroll
      for (int r = 0; r < 4; r++)
        outp[(size_t)(rbase + r) * 1024 + col] = acc[mi][ni][r];
    }
  }
}

// ---------------- flash attention, LDS-staged K/V shared by 4 waves ----------------
// Q,K: bf16 [bh][l][64]; Vt: bf16 tiled [bh][l/32][d][l%32]; O: bf16 [b*2048+l][h*64+d]
__global__ __launch_bounds__(256) void attn_kernel(const unsigned short* __restrict__ Q,
                                                   const unsigned short* __restrict__ K,
                                                   const unsigned short* __restrict__ Vt,
                                                   unsigned short* __restrict__ O) {
  __shared__ unsigned short Ks[2][2048];
  __shared__ unsigned short Vs[2][2048];
  const int tid = threadIdx.x;
  const int lane = tid & 63;
  const int w = tid >> 6;      // 0..3 = q-tile
  const int n = blockIdx.x;
  const int bh = (n & 7) * 8 + (n >> 7);   // XCD c owns bh [8c, 8c+8): 4MB K/V per L2
  const int qg = (n >> 3) & 15;
  const int q0 = qg * 128 + w * 32;
  const int lo = lane & 31, hi = lane >> 5;

  const unsigned short* qp = Q + ((size_t)bh * 2048 + q0 + lo) * 64 + (hi << 3);
  short8 qf[4];
#pragma unroll
  for (int c = 0; c < 4; c++)
    qf[c] = *reinterpret_cast<const short8*>(qp + c * 16);

  f32x16 o0 = {0.f,0.f,0.f,0.f,0.f,0.f,0.f,0.f,0.f,0.f,0.f,0.f,0.f,0.f,0.f,0.f};
  f32x16 o1 = {0.f,0.f,0.f,0.f,0.f,0.f,0.f,0.f,0.f,0.f,0.f,0.f,0.f,0.f,0.f,0.f};
  float mrun = -1e30f, lsum = 0.0f;
  const float KS = 1.44269504088896f / 16.0f;  // log2(e)/SCALE

  const char* Kg = (const char*)(K + (size_t)bh * 2048 * 64);
  const char* Vg = (const char*)(Vt + (size_t)bh * 131072);

  const int p16 = tid * 16;
  const int lswz = p16 ^ (((p16 >> 7) & 7) << 4);  // logical byte within tile
  const int koff = lswz;                            // K: logical == global layout
  const int voff = (lswz >> 7) * 64 + ((lswz >> 6) & 1) * 2048 + (lswz & 63);

  const int sK = (lo & 7) << 4;
  int kix[4];
#pragma unroll
  for (int c = 0; c < 4; c++)
    kix[c] = ((lo * 128 + hi * 16 + c * 32) ^ sK) >> 1;   // K[key=lo][d=hi*8 + c*16]
  int vix[4];
  vix[0] = ((lo * 128 + hi * 16) ^ sK) >> 1;        // V[d=lo   ][key=hi*8]
  vix[1] = ((lo * 128 + 32 + hi * 16) ^ sK) >> 1;   // V[d=lo   ][key=hi*8+16]
  vix[2] = ((lo * 128 + 64 + hi * 16) ^ sK) >> 1;   // V[d=lo+32][key=hi*8]
  vix[3] = ((lo * 128 + 96 + hi * 16) ^ sK) >> 1;   // V[d=lo+32][key=hi*8+16]

  auto STAGE = [&](int kt, int buf) {
    gload_lds16(Kg + (size_t)kt * 4096 + koff, &Ks[buf][tid * 8]);
    gload_lds16(Vg + (size_t)kt * 4096 + voff, &Vs[buf][tid * 8]);
  };

  STAGE(0, 0);
  __syncthreads();

  for (int kt = 0; kt < 64; kt++) {
    const int buf = kt & 1;
    const int nx = (kt < 63) ? kt + 1 : 63;
    STAGE(nx, buf ^ 1);  // in flight across this iteration; drained by __syncthreads

    short8 kc[4], vc[4];
#pragma unroll
    for (int c = 0; c < 4; c++)
      kc[c] = *reinterpret_cast<const short8*>(&Ks[buf][kix[c]]);
#pragma unroll
    for (int c = 0; c < 4; c++)
      vc[c] = *reinterpret_cast<const short8*>(&Vs[buf][vix[c]]);

    // QK^T (swapped: A=K so D rows = keys, D cols = q)
    f32x16 s = {0.f,0.f,0.f,0.f,0.f,0.f,0.f,0.f,0.f,0.f,0.f,0.f,0.f,0.f,0.f,0.f};
    __builtin_amdgcn_s_setprio(1);
#pragma unroll
    for (int c = 0; c < 4; c++)
      s = __builtin_amdgcn_mfma_f32_32x32x16_bf16(kc[c], qf[c], s, 0, 0, 0);
    __builtin_amdgcn_s_setprio(0);

    // online softmax (defer-max T13); cross-lane merges via permlane32_swap
    float m01 = fmaxf(s[0], s[1]), m23 = fmaxf(s[2], s[3]);
    float m45 = fmaxf(s[4], s[5]), m67 = fmaxf(s[6], s[7]);
    float m89 = fmaxf(s[8], s[9]), mab = fmaxf(s[10], s[11]);
    float mcd = fmaxf(s[12], s[13]), mef = fmaxf(s[14], s[15]);
    float cmax = fmaxf(fmaxf(fmaxf(m01, m23), fmaxf(m45, m67)),
                       fmaxf(fmaxf(m89, mab), fmaxf(mcd, mef)));
    {
      int2v mm = pl32(__float_as_int(cmax), __float_as_int(cmax));
      cmax = fmaxf(__int_as_float(mm.x), __int_as_float(mm.y));
    }

    if (__any(cmax > mrun + 128.0f)) {  // 128 raw = 8 post-scale nats
      const float mnew = fmaxf(mrun, cmax);
      const float alpha = __builtin_amdgcn_exp2f((mrun - mnew) * KS);
      lsum *= alpha;
#pragma unroll
      for (int r = 0; r < 16; r++) {
        const int row = (r & 3) + ((r >> 2) << 3) + (hi << 2);
        const float ar = __shfl(alpha, row);
        o0[r] *= ar;
        o1[r] *= ar;
      }
      mrun = mnew;
    }

    float pr[16];
    const float mk = mrun * KS;
#pragma unroll
    for (int r = 0; r < 16; r++)
      pr[r] = __builtin_amdgcn_exp2f(__builtin_fmaf(s[r], KS, -mk));
    float c01 = (pr[0] + pr[1]) + (pr[2] + pr[3]);
    float c23 = (pr[4] + pr[5]) + (pr[6] + pr[7]);
    float c45 = (pr[8] + pr[9]) + (pr[10] + pr[11]);
    float c67 = (pr[12] + pr[13]) + (pr[14] + pr[15]);
    float csum = (c01 + c23) + (c45 + c67);
    {
      int2v ss = pl32(__float_as_int(csum), __float_as_int(csum));
      csum = __int_as_float(ss.x) + __int_as_float(ss.y);
    }
    lsum += csum;

    // pack P -> bf16 PV A-fragments via permlane32_swap
    const uint32_t c0 = cvtpk(pr[0], pr[1]),   c1 = cvtpk(pr[2], pr[3]);
    const uint32_t c2 = cvtpk(pr[4], pr[5]),   c3 = cvtpk(pr[6], pr[7]);
    const uint32_t c4 = cvtpk(pr[8], pr[9]),   c5 = cvtpk(pr[10], pr[11]);
    const uint32_t c6 = cvtpk(pr[12], pr[13]), c7 = cvtpk(pr[14], pr[15]);
    int2v s02 = pl32((int)c0, (int)c2);
    int2v s13 = pl32((int)c1, (int)c3);
    int2v s46 = pl32((int)c4, (int)c6);
    int2v s57 = pl32((int)c5, (int)c7);
    union { uint32_t u[4]; short8 v; } pa, pb;
    pa.u[0] = (uint32_t)s02.x; pa.u[1] = (uint32_t)s13.x;
    pa.u[2] = (uint32_t)s02.y; pa.u[3] = (uint32_t)s13.y;
    pb.u[0] = (uint32_t)s46.x; pb.u[1] = (uint32_t)s57.x;
    pb.u[2] = (uint32_t)s46.y; pb.u[3] = (uint32_t)s57.y;

    // PV
    __builtin_amdgcn_s_setprio(1);
    o0 = __builtin_amdgcn_mfma_f32_32x32x16_bf16(pa.v, vc[0], o0, 0, 0, 0);
    o0 = __builtin_amdgcn_mfma_f32_32x32x16_bf16(pb.v, vc[1], o0, 0, 0, 0);
    o1 = __builtin_amdgcn_mfma_f32_32x32x16_bf16(pa.v, vc[2], o1, 0, 0, 0);
    o1 = __builtin_amdgcn_mfma_f32_32x32x16_bf16(pb.v, vc[3], o1, 0, 0, 0);
    __builtin_amdgcn_s_setprio(0);

    __syncthreads();  // drains stage (vmcnt 0) + this wave's ds_reads (lgkmcnt 0)
  }

  const int b = bh >> 4, h = bh & 15;
#pragma unroll
  for (int r = 0; r < 16; r++) {
    const int row = (r & 3) + ((r >> 2) << 3) + (hi << 2);
    const float lr = __shfl(lsum, row);
    const float inv = __builtin_amdgcn_rcpf(lr);
    const size_t base = ((size_t)b * 2048 + q0 + row) * 1024 + h * 64 + lo;
    O[base] = f2bf(o0[r] * inv);
    O[base + 32] = f2bf(o1[r] * inv);
  }
}

// ---------------- residual + LayerNorm ----------------
__global__ __launch_bounds__(256) void ln_kernel(const float* __restrict__ fc,
                                                 const float* __restrict__ qa,
                                                 const float* __restrict__ qs,
                                                 const float* __restrict__ gamma,
                                                 const float* __restrict__ beta,
                                                 float* __restrict__ out) {
  const int m = blockIdx.x;
  const int t = threadIdx.x;
  const size_t base = (size_t)m * 1024 + t * 4;
  float4 x = *reinterpret_cast<const float4*>(fc + base);
  const float4 a = *reinterpret_cast<const float4*>(qa + base);
  const float4 b = *reinterpret_cast<const float4*>(qs + base);
  x.x += a.x + b.x; x.y += a.y + b.y; x.z += a.z + b.z; x.w += a.w + b.w;
  float s1 = x.x + x.y + x.z + x.w;
  float s2 = x.x * x.x + x.y * x.y + x.z * x.z + x.w * x.w;
#pragma unroll
  for (int off = 1; off < 64; off <<= 1) {
    s1 += __shfl_xor(s1, off);
    s2 += __shfl_xor(s2, off);
  }
  __shared__ float sh[8];
  const int w = t >> 6, lane = t & 63;
  if (lane == 0) { sh[w] = s1; sh[4 + w] = s2; }
  __syncthreads();
  s1 = sh[0] + sh[1] + sh[2] + sh[3];
  s2 = sh[4] + sh[5] + sh[6] + sh[7];
  const float mu = s1 * (1.0f / 1024.0f);
  const float var = s2 * (1.0f / 1024.0f) - mu * mu;
  const float rs = rsqrtf(var + 1e-6f);
  const float4 g = *reinterpret_cast<const float4*>(gamma + t * 4);
  const float4 be = *reinterpret_cast<const float4*>(beta + t * 4);
  float4 y;
  y.x = (x.x - mu) * rs * g.x + be.x;
  y.y = (x.y - mu) * rs * g.y + be.y;
  y.z = (x.z - mu) * rs * g.z + be.z;
  y.w = (x.w - mu) * rs * g.w + be.w;
  *reinterpret_cast<float4*>(out + base) = y;
}

__global__ void sentinel_kernel(float* out, int n) {
  int i = blockIdx.x * blockDim.x + threadIdx.x;
  if (i < n) out[i] = 1234.5f;
}

extern "C" void kernel_launch(void* const* d_in, const int* in_sizes, int n_in,
                              void* d_out, int out_size, void* d_ws, size_t ws_size,
                              hipStream_t stream) {
  const size_t MB = 1024ull * 1024ull;
  if (ws_size < 174 * MB) {  // distinctive failure mode if scratch too small
    sentinel_kernel<<<(out_size + 255) / 256, 256, 0, stream>>>((float*)d_out, out_size);
    return;
  }
  const float* fin[6];
  for (int i = 0; i < 6; i++) fin[i] = (const float*)d_in[i];
  const float* Wf[7];
  for (int i = 0; i < 7; i++) Wf[i] = (const float*)d_in[6 + i];
  const float* gamma = (const float*)d_in[13];
  const float* beta = (const float*)d_in[14];

  char* ws = (char*)d_ws;
  unsigned short* Abf[6];
  for (int i = 0; i < 6; i++) Abf[i] = (unsigned short*)(ws + (size_t)i * 16 * MB);
  unsigned short* WqT = (unsigned short*)(ws + 96 * MB);   // [1024][2048]
  unsigned short* WkT = (unsigned short*)(ws + 100 * MB);
  unsigned short* WvT = (unsigned short*)(ws + 104 * MB);
  unsigned short* WfcT = (unsigned short*)(ws + 108 * MB); // [1024][1024]
  unsigned short* Qb = (unsigned short*)(ws + 110 * MB);   // [64][2048][64]
  unsigned short* Kb = (unsigned short*)(ws + 126 * MB);
  unsigned short* Vtb = (unsigned short*)(ws + 142 * MB);  // [64][64][64][32] tiled
  unsigned short* Ob = (unsigned short*)(ws + 158 * MB);   // [8192][1024]
  float* fcout = (float*)(ws + 16 * MB);  // aliases Abf[1],Abf[2] (dead after proj GEMMs)

  CvtArgs ca;
  for (int i = 0; i < 6; i++) { ca.in[i] = fin[i]; ca.out[i] = Abf[i]; }
  cvt_kernel<<<dim3(1024, 6), 256, 0, stream>>>(ca, 2097152);

  TcvtArgs ta;
  const int wsel[7] = {0, 3, 1, 4, 2, 5, 6};
  unsigned short* wdst[7] = {WqT, WqT, WkT, WkT, WvT, WvT, WfcT};
  for (int i = 0; i < 7; i++) {
    ta.src[i] = Wf[wsel[i]];
    ta.dst[i] = wdst[i];
    ta.stride[i] = (i < 6) ? 2048 : 1024;
    ta.koff[i] = (i < 6) ? ((i & 1) ? 1024 : 0) : 0;
  }
  tcvt_kernel<<<dim3(32, 32, 7), 256, 0, stream>>>(ta);

  G3Args g3;
  g3.A1[0] = Abf[0]; g3.A2[0] = Abf[3]; g3.WT[0] = WqT; g3.out[0] = Qb;
  g3.A1[1] = Abf[1]; g3.A2[1] = Abf[4]; g3.WT[1] = WkT; g3.out[1] = Kb;
  g3.A1[2] = Abf[2]; g3.A2[2] = Abf[5]; g3.WT[2] = WvT; g3.out[2] = Vtb;
  gemm3_kernel<<<384, 512, 0, stream>>>(g3);

  attn_kernel<<<1024, 256, 0, stream>>>(Qb, Kb, Vtb, Ob);

  gemmfc_kernel<<<512, 256, 0, stream>>>(Ob, WfcT, fcout);

  ln_kernel<<<8192, 256, 0, stream>>>(fcout, fin[0], fin[3], gamma, beta, (float*)d_out);
}

// Round 3
// 349.375 us; speedup vs baseline: 1.0769x; 1.0769x over previous
//
#include <hip/hip_runtime.h>
#include <hip/hip_bf16.h>
#include <stdint.h>

typedef __attribute__((ext_vector_type(4))) float f32x4;
typedef __attribute__((ext_vector_type(16))) float f32x16;
typedef __attribute__((ext_vector_type(8))) short short8;
typedef __attribute__((ext_vector_type(2))) int int2v;

#define DEV static __device__ __forceinline__

DEV unsigned short f2bf(float f) {
  unsigned u = __float_as_uint(f);
  u += 0x7fffu + ((u >> 16) & 1u);
  return (unsigned short)(u >> 16);
}

DEV uint32_t cvtpk(float a, float b) {  // {lo: bf16(a), hi: bf16(b)}
  uint32_t r;
  asm("v_cvt_pk_bf16_f32 %0, %1, %2" : "=v"(r) : "v"(a), "v"(b));
  return r;
}

// v_permlane32_swap_b32: r.x = {a[0:31], b[0:31] in hi lanes}, r.y = {a[32:63] in lo lanes, b[32:63]}
DEV int2v pl32(int a, int b) {
  return __builtin_amdgcn_permlane32_swap(a, b, false, false);
}

typedef const __attribute__((address_space(1))) void* gas_ptr;
typedef __attribute__((address_space(3))) void* las_ptr;

DEV void gload_lds16(const void* g, void* l) {
  __builtin_amdgcn_global_load_lds((gas_ptr)g, (las_ptr)l, 16, 0, 0);
}

// ---------------- f32 -> bf16 elementwise convert, all 6 tensors in one launch ----------------
struct CvtArgs {
  const float* in[6];
  unsigned short* out[6];
};

__global__ __launch_bounds__(256) void cvt_kernel(CvtArgs a, int n4) {
  const float* __restrict__ in = a.in[blockIdx.y];
  unsigned short* __restrict__ out = a.out[blockIdx.y];
  int idx = blockIdx.x * blockDim.x + threadIdx.x;
  int stride = gridDim.x * blockDim.x;
  for (int i = idx; i < n4; i += stride) {
    float4 v = reinterpret_cast<const float4*>(in)[i];
    ushort4 o;
    o.x = f2bf(v.x); o.y = f2bf(v.y); o.z = f2bf(v.z); o.w = f2bf(v.w);
    reinterpret_cast<ushort4*>(out)[i] = o;
  }
}

// ------------- weight transpose+convert: src f32 [1024 k][1024 n] -> dst bf16 [n][k], 7 in one ----
struct TcvtArgs {
  const float* src[7];
  unsigned short* dst[7];
  int stride[7];
  int koff[7];
};

__global__ __launch_bounds__(256) void tcvt_kernel(TcvtArgs a) {
  const int which = blockIdx.z;
  const float* __restrict__ src = a.src[which];
  unsigned short* __restrict__ dst = a.dst[which];
  const int dstStride = a.stride[which], kOff = a.koff[which];
  __shared__ float tile[32][33];
  int tx = threadIdx.x & 31;   // 0..31
  int ty = threadIdx.x >> 5;   // 0..7
  int n0 = blockIdx.x * 32;
  int k0 = blockIdx.y * 32;
#pragma unroll
  for (int i = 0; i < 4; i++)
    tile[ty + 8 * i][tx] = src[(size_t)(k0 + ty + 8 * i) * 1024 + n0 + tx];
  __syncthreads();
#pragma unroll
  for (int i = 0; i < 4; i++) {
    int n = n0 + ty + 8 * i;
    dst[(size_t)n * dstStride + kOff + k0 + tx] = f2bf(tile[tx][ty + 8 * i]);
  }
}

// ---------------- merged Q/K/V projection GEMM (proven 128^2 structure) ----------------
// C[8192 x 1024] = concat_k(A1,A2) @ W  (W transposed [n][k], Ktot=2048, ksplit=1024)
// XCD-chunked swizzle: each XCD owns 192 consecutive logical blocks -> A-slab reused
// across its 8 nt from the XCD's own L2; 4MB weight resident per-XCD.
// NOTE (R1/R2 lesson): 256^2 8-wave pipelined variants run ~900 TF per-active-CU but the
// 384-block grid quantizes to 75% CU util -> slower overall.  128^2 multi-block keeps
// ~100% util at 754 TF; grid shape matches the problem.
struct G3Args {
  const unsigned short* A1[3];
  const unsigned short* A2[3];
  const unsigned short* WT[3];
  unsigned short* out[3];
};

__global__ __launch_bounds__(256) void gemm3_kernel(G3Args g) {
  __shared__ unsigned short As[128 * 32];
  __shared__ unsigned short Bs[128 * 32];
  const int orig = blockIdx.x;
  const int swz = (orig & 7) * 192 + (orig >> 3);  // 1536 blocks, bijective
  const int which = swz >> 9;
  const int bid = swz & 511;
  const unsigned short* __restrict__ A1 = g.A1[which];
  const unsigned short* __restrict__ A2 = g.A2[which];
  const unsigned short* __restrict__ WT = g.WT[which];
  unsigned short* __restrict__ outp = g.out[which];

  const int tid = threadIdx.x;
  const int lane = tid & 63;
  const int w = tid >> 6;
  const int mt = bid >> 3, nt = bid & 7;
  const int m0 = mt * 128, n0 = nt * 128;

  const int srow = (w << 4) + (lane >> 2);
  const int scol = (lane & 3) << 3;

  f32x4 zero4 = {0.f, 0.f, 0.f, 0.f};
  f32x4 acc[4][4];
#pragma unroll
  for (int mi = 0; mi < 4; mi++)
#pragma unroll
    for (int ni = 0; ni < 4; ni++) acc[mi][ni] = zero4;

  const int wr = w >> 1, wc = w & 1;
  const int arow = (wr << 6) + (lane & 15);
  const int brow = (wc << 6) + (lane & 15);
  const int kcol = (lane >> 4) << 3;

  for (int kt = 0; kt < 64; kt++) {
    const int kk = kt << 5;
    const unsigned short* Asrc;
    int ka;
    if (kk < 1024) { Asrc = A1; ka = kk; } else { Asrc = A2; ka = kk - 1024; }
#pragma unroll
    for (int p = 0; p < 2; p++) {
      const unsigned short* gp = Asrc + (size_t)(m0 + p * 64 + srow) * 1024 + ka + scol;
      gload_lds16(gp, &As[(p * 64 + srow) * 32 + scol]);
    }
#pragma unroll
    for (int p = 0; p < 2; p++) {
      const unsigned short* gp = WT + (size_t)(n0 + p * 64 + srow) * 2048 + kk + scol;
      gload_lds16(gp, &Bs[(p * 64 + srow) * 32 + scol]);
    }
    __syncthreads();

    short8 av[4], bv[4];
#pragma unroll
    for (int mi = 0; mi < 4; mi++)
      av[mi] = *reinterpret_cast<const short8*>(&As[(arow + mi * 16) * 32 + kcol]);
#pragma unroll
    for (int ni = 0; ni < 4; ni++)
      bv[ni] = *reinterpret_cast<const short8*>(&Bs[(brow + ni * 16) * 32 + kcol]);
#pragma unroll
    for (int mi = 0; mi < 4; mi++)
#pragma unroll
      for (int ni = 0; ni < 4; ni++)
        acc[mi][ni] = __builtin_amdgcn_mfma_f32_16x16x32_bf16(av[mi], bv[ni], acc[mi][ni], 0, 0, 0);
    __syncthreads();
  }

  // epilogue: D layout col = lane&15, row = (lane>>4)*4 + reg
#pragma unroll
  for (int mi = 0; mi < 4; mi++) {
#pragma unroll
    for (int ni = 0; ni < 4; ni++) {
      const int col = n0 + (wc << 6) + ni * 16 + (lane & 15);
      const int rbase = m0 + (wr << 6) + mi * 16 + ((lane >> 4) << 2);
      const int h = col >> 6, d = col & 63;
      if (which < 2) {
#pragma unroll
        for (int r = 0; r < 4; r++) {
          const int m = rbase + r;
          const int b = m >> 11, l = m & 2047;
          outp[((size_t)((b * 16 + h) * 2048 + l)) * 64 + d] = f2bf(acc[mi][ni][r]);
        }
      } else {
        // V tiled: [bh][l/32][d][l%32], tile = 64x32 = 4KB contiguous
        const int m = rbase;
        const int b = m >> 11, l = m & 2047;
        const int bh = b * 16 + h;
        ushort4 o;
        o.x = f2bf(acc[mi][ni][0]);
        o.y = f2bf(acc[mi][ni][1]);
        o.z = f2bf(acc[mi][ni][2]);
        o.w = f2bf(acc[mi][ni][3]);
        *reinterpret_cast<ushort4*>(
            outp + (size_t)(bh * 64 + (l >> 5)) * 2048 + d * 32 + (l & 31)) = o;
      }
    }
  }
}

// ---------------- fc GEMM: C[8192 x 1024] = A @ W + q_a + q_s (residual fused), f32 out -------
// Residual reads hide under MFMA (kernel is compute-bound with idle memory pipes); this
// halves ln_kernel's HBM traffic.
__global__ __launch_bounds__(256) void gemmfc_kernel(const unsigned short* __restrict__ A1,
                                                     const unsigned short* __restrict__ WT,
                                                     const float* __restrict__ qa,
                                                     const float* __restrict__ qs,
                                                     float* __restrict__ outp) {
  __shared__ unsigned short As[128 * 32];
  __shared__ unsigned short Bs[128 * 32];
  const int orig = blockIdx.x;
  const int bid = (orig & 7) * 64 + (orig >> 3);  // 512 blocks, bijective XCD chunk
  const int tid = threadIdx.x;
  const int lane = tid & 63;
  const int w = tid >> 6;
  const int mt = bid >> 3, nt = bid & 7;
  const int m0 = mt * 128, n0 = nt * 128;

  const int srow = (w << 4) + (lane >> 2);
  const int scol = (lane & 3) << 3;

  f32x4 zero4 = {0.f, 0.f, 0.f, 0.f};
  f32x4 acc[4][4];
#pragma unroll
  for (int mi = 0; mi < 4; mi++)
#pragma unroll
    for (int ni = 0; ni < 4; ni++) acc[mi][ni] = zero4;

  const int wr = w >> 1, wc = w & 1;
  const int arow = (wr << 6) + (lane & 15);
  const int brow = (wc << 6) + (lane & 15);
  const int kcol = (lane >> 4) << 3;

  for (int kt = 0; kt < 32; kt++) {
    const int kk = kt << 5;
#pragma unroll
    for (int p = 0; p < 2; p++) {
      const unsigned short* gp = A1 + (size_t)(m0 + p * 64 + srow) * 1024 + kk + scol;
      gload_lds16(gp, &As[(p * 64 + srow) * 32 + scol]);
    }
#pragma unroll
    for (int p = 0; p < 2; p++) {
      const unsigned short* gp = WT + (size_t)(n0 + p * 64 + srow) * 1024 + kk + scol;
      gload_lds16(gp, &Bs[(p * 64 + srow) * 32 + scol]);
    }
    __syncthreads();

    short8 av[4], bv[4];
#pragma unroll
    for (int mi = 0; mi < 4; mi++)
      av[mi] = *reinterpret_cast<const short8*>(&As[(arow + mi * 16) * 32 + kcol]);
#pragma unroll
    for (int ni = 0; ni < 4; ni++)
      bv[ni] = *reinterpret_cast<const short8*>(&Bs[(brow + ni * 16) * 32 + kcol]);
#pragma unroll
    for (int mi = 0; mi < 4; mi++)
#pragma unroll
      for (int ni = 0; ni < 4; ni++)
        acc[mi][ni] = __builtin_amdgcn_mfma_f32_16x16x32_bf16(av[mi], bv[ni], acc[mi][ni], 0, 0, 0);
    __syncthreads();
  }

#pragma unroll
  for (int mi = 0; mi < 4; mi++) {
#pragma unroll
    for (int ni = 0; ni < 4; ni++) {
      const int col = n0 + (wc << 6) + ni * 16 + (lane & 15);
      const int rbase = m0 + (wr << 6) + mi * 16 + ((lane >> 4) << 2);
#pragma unroll
      for (int r = 0; r < 4; r++) {
        const size_t idx = (size_t)(rbase + r) * 1024 + col;
        outp[idx] = acc[mi][ni][r] + qa[idx] + qs[idx];
      }
    }
  }
}

// ---------------- flash attention, LDS-staged K/V shared by 4 waves ----------------
// Q,K: bf16 [bh][l][64]; Vt: bf16 tiled [bh][l/32][d][l%32]; O: bf16 [b*2048+l][h*64+d]
__global__ __launch_bounds__(256) void attn_kernel(const unsigned short* __restrict__ Q,
                                                   const unsigned short* __restrict__ K,
                                                   const unsigned short* __restrict__ Vt,
                                                   unsigned short* __restrict__ O) {
  __shared__ unsigned short Ks[2][2048];
  __shared__ unsigned short Vs[2][2048];
  const int tid = threadIdx.x;
  const int lane = tid & 63;
  const int w = tid >> 6;      // 0..3 = q-tile
  const int n = blockIdx.x;
  const int bh = (n & 7) * 8 + (n >> 7);   // XCD c owns bh [8c, 8c+8): 4MB K/V per L2
  const int qg = (n >> 3) & 15;
  const int q0 = qg * 128 + w * 32;
  const int lo = lane & 31, hi = lane >> 5;

  const unsigned short* qp = Q + ((size_t)bh * 2048 + q0 + lo) * 64 + (hi << 3);
  short8 qf[4];
#pragma unroll
  for (int c = 0; c < 4; c++)
    qf[c] = *reinterpret_cast<const short8*>(qp + c * 16);

  f32x16 o0 = {0.f,0.f,0.f,0.f,0.f,0.f,0.f,0.f,0.f,0.f,0.f,0.f,0.f,0.f,0.f,0.f};
  f32x16 o1 = {0.f,0.f,0.f,0.f,0.f,0.f,0.f,0.f,0.f,0.f,0.f,0.f,0.f,0.f,0.f,0.f};
  float mrun = -1e30f, lsum = 0.0f;
  const float KS = 1.44269504088896f / 16.0f;  // log2(e)/SCALE

  const char* Kg = (const char*)(K + (size_t)bh * 2048 * 64);
  const char* Vg = (const char*)(Vt + (size_t)bh * 131072);

  const int p16 = tid * 16;
  const int lswz = p16 ^ (((p16 >> 7) & 7) << 4);  // logical byte within tile
  const int koff = lswz;                            // K: logical == global layout
  const int voff = (lswz >> 7) * 64 + ((lswz >> 6) & 1) * 2048 + (lswz & 63);

  const int sK = (lo & 7) << 4;
  int kix[4];
#pragma unroll
  for (int c = 0; c < 4; c++)
    kix[c] = ((lo * 128 + hi * 16 + c * 32) ^ sK) >> 1;   // K[key=lo][d=hi*8 + c*16]
  int vix[4];
  vix[0] = ((lo * 128 + hi * 16) ^ sK) >> 1;        // V[d=lo   ][key=hi*8]
  vix[1] = ((lo * 128 + 32 + hi * 16) ^ sK) >> 1;   // V[d=lo   ][key=hi*8+16]
  vix[2] = ((lo * 128 + 64 + hi * 16) ^ sK) >> 1;   // V[d=lo+32][key=hi*8]
  vix[3] = ((lo * 128 + 96 + hi * 16) ^ sK) >> 1;   // V[d=lo+32][key=hi*8+16]

  auto STAGE = [&](int kt, int buf) {
    gload_lds16(Kg + (size_t)kt * 4096 + koff, &Ks[buf][tid * 8]);
    gload_lds16(Vg + (size_t)kt * 4096 + voff, &Vs[buf][tid * 8]);
  };

  STAGE(0, 0);
  __syncthreads();

  for (int kt = 0; kt < 64; kt++) {
    const int buf = kt & 1;
    const int nx = (kt < 63) ? kt + 1 : 63;
    STAGE(nx, buf ^ 1);  // in flight across this iteration; drained by __syncthreads

    short8 kc[4], vc[4];
#pragma unroll
    for (int c = 0; c < 4; c++)
      kc[c] = *reinterpret_cast<const short8*>(&Ks[buf][kix[c]]);
#pragma unroll
    for (int c = 0; c < 4; c++)
      vc[c] = *reinterpret_cast<const short8*>(&Vs[buf][vix[c]]);

    // QK^T (swapped: A=K so D rows = keys, D cols = q)
    f32x16 s = {0.f,0.f,0.f,0.f,0.f,0.f,0.f,0.f,0.f,0.f,0.f,0.f,0.f,0.f,0.f,0.f};
    __builtin_amdgcn_s_setprio(1);
#pragma unroll
    for (int c = 0; c < 4; c++)
      s = __builtin_amdgcn_mfma_f32_32x32x16_bf16(kc[c], qf[c], s, 0, 0, 0);
    __builtin_amdgcn_s_setprio(0);

    // online softmax (defer-max T13); cross-lane merges via permlane32_swap
    float m01 = fmaxf(s[0], s[1]), m23 = fmaxf(s[2], s[3]);
    float m45 = fmaxf(s[4], s[5]), m67 = fmaxf(s[6], s[7]);
    float m89 = fmaxf(s[8], s[9]), mab = fmaxf(s[10], s[11]);
    float mcd = fmaxf(s[12], s[13]), mef = fmaxf(s[14], s[15]);
    float cmax = fmaxf(fmaxf(fmaxf(m01, m23), fmaxf(m45, m67)),
                       fmaxf(fmaxf(m89, mab), fmaxf(mcd, mef)));
    {
      int2v mm = pl32(__float_as_int(cmax), __float_as_int(cmax));
      cmax = fmaxf(__int_as_float(mm.x), __int_as_float(mm.y));
    }

    if (__any(cmax > mrun + 128.0f)) {  // 128 raw = 8 post-scale nats
      const float mnew = fmaxf(mrun, cmax);
      const float alpha = __builtin_amdgcn_exp2f((mrun - mnew) * KS);
      lsum *= alpha;
#pragma unroll
      for (int r = 0; r < 16; r++) {
        const int row = (r & 3) + ((r >> 2) << 3) + (hi << 2);
        const float ar = __shfl(alpha, row);
        o0[r] *= ar;
        o1[r] *= ar;
      }
      mrun = mnew;
    }

    float pr[16];
    const float mk = mrun * KS;
#pragma unroll
    for (int r = 0; r < 16; r++)
      pr[r] = __builtin_amdgcn_exp2f(__builtin_fmaf(s[r], KS, -mk));
    float c01 = (pr[0] + pr[1]) + (pr[2] + pr[3]);
    float c23 = (pr[4] + pr[5]) + (pr[6] + pr[7]);
    float c45 = (pr[8] + pr[9]) + (pr[10] + pr[11]);
    float c67 = (pr[12] + pr[13]) + (pr[14] + pr[15]);
    float csum = (c01 + c23) + (c45 + c67);
    {
      int2v ss = pl32(__float_as_int(csum), __float_as_int(csum));
      csum = __int_as_float(ss.x) + __int_as_float(ss.y);
    }
    lsum += csum;

    // pack P -> bf16 PV A-fragments via permlane32_swap
    const uint32_t c0 = cvtpk(pr[0], pr[1]),   c1 = cvtpk(pr[2], pr[3]);
    const uint32_t c2 = cvtpk(pr[4], pr[5]),   c3 = cvtpk(pr[6], pr[7]);
    const uint32_t c4 = cvtpk(pr[8], pr[9]),   c5 = cvtpk(pr[10], pr[11]);
    const uint32_t c6 = cvtpk(pr[12], pr[13]), c7 = cvtpk(pr[14], pr[15]);
    int2v s02 = pl32((int)c0, (int)c2);
    int2v s13 = pl32((int)c1, (int)c3);
    int2v s46 = pl32((int)c4, (int)c6);
    int2v s57 = pl32((int)c5, (int)c7);
    union { uint32_t u[4]; short8 v; } pa, pb;
    pa.u[0] = (uint32_t)s02.x; pa.u[1] = (uint32_t)s13.x;
    pa.u[2] = (uint32_t)s02.y; pa.u[3] = (uint32_t)s13.y;
    pb.u[0] = (uint32_t)s46.x; pb.u[1] = (uint32_t)s57.x;
    pb.u[2] = (uint32_t)s46.y; pb.u[3] = (uint32_t)s57.y;

    // PV
    __builtin_amdgcn_s_setprio(1);
    o0 = __builtin_amdgcn_mfma_f32_32x32x16_bf16(pa.v, vc[0], o0, 0, 0, 0);
    o0 = __builtin_amdgcn_mfma_f32_32x32x16_bf16(pb.v, vc[1], o0, 0, 0, 0);
    o1 = __builtin_amdgcn_mfma_f32_32x32x16_bf16(pa.v, vc[2], o1, 0, 0, 0);
    o1 = __builtin_amdgcn_mfma_f32_32x32x16_bf16(pb.v, vc[3], o1, 0, 0, 0);
    __builtin_amdgcn_s_setprio(0);

    __syncthreads();  // drains stage (vmcnt 0) + this wave's ds_reads (lgkmcnt 0)
  }

  const int b = bh >> 4, h = bh & 15;
#pragma unroll
  for (int r = 0; r < 16; r++) {
    const int row = (r & 3) + ((r >> 2) << 3) + (hi << 2);
    const float lr = __shfl(lsum, row);
    const float inv = __builtin_amdgcn_rcpf(lr);
    const size_t base = ((size_t)b * 2048 + q0 + row) * 1024 + h * 64 + lo;
    O[base] = f2bf(o0[r] * inv);
    O[base + 32] = f2bf(o1[r] * inv);
  }
}

// ---------------- LayerNorm (residual already folded into fc by gemmfc) ----------------
__global__ __launch_bounds__(256) void ln_kernel(const float* __restrict__ fc,
                                                 const float* __restrict__ gamma,
                                                 const float* __restrict__ beta,
                                                 float* __restrict__ out) {
  const int m = blockIdx.x;
  const int t = threadIdx.x;
  const size_t base = (size_t)m * 1024 + t * 4;
  float4 x = *reinterpret_cast<const float4*>(fc + base);
  float s1 = x.x + x.y + x.z + x.w;
  float s2 = x.x * x.x + x.y * x.y + x.z * x.z + x.w * x.w;
#pragma unroll
  for (int off = 1; off < 64; off <<= 1) {
    s1 += __shfl_xor(s1, off);
    s2 += __shfl_xor(s2, off);
  }
  __shared__ float sh[8];
  const int w = t >> 6, lane = t & 63;
  if (lane == 0) { sh[w] = s1; sh[4 + w] = s2; }
  __syncthreads();
  s1 = sh[0] + sh[1] + sh[2] + sh[3];
  s2 = sh[4] + sh[5] + sh[6] + sh[7];
  const float mu = s1 * (1.0f / 1024.0f);
  const float var = s2 * (1.0f / 1024.0f) - mu * mu;
  const float rs = rsqrtf(var + 1e-6f);
  const float4 g = *reinterpret_cast<const float4*>(gamma + t * 4);
  const float4 be = *reinterpret_cast<const float4*>(beta + t * 4);
  float4 y;
  y.x = (x.x - mu) * rs * g.x + be.x;
  y.y = (x.y - mu) * rs * g.y + be.y;
  y.z = (x.z - mu) * rs * g.z + be.z;
  y.w = (x.w - mu) * rs * g.w + be.w;
  *reinterpret_cast<float4*>(out + base) = y;
}

__global__ void sentinel_kernel(float* out, int n) {
  int i = blockIdx.x * blockDim.x + threadIdx.x;
  if (i < n) out[i] = 1234.5f;
}

extern "C" void kernel_launch(void* const* d_in, const int* in_sizes, int n_in,
                              void* d_out, int out_size, void* d_ws, size_t ws_size,
                              hipStream_t stream) {
  const size_t MB = 1024ull * 1024ull;
  if (ws_size < 174 * MB) {  // distinctive failure mode if scratch too small
    sentinel_kernel<<<(out_size + 255) / 256, 256, 0, stream>>>((float*)d_out, out_size);
    return;
  }
  const float* fin[6];
  for (int i = 0; i < 6; i++) fin[i] = (const float*)d_in[i];
  const float* Wf[7];
  for (int i = 0; i < 7; i++) Wf[i] = (const float*)d_in[6 + i];
  const float* gamma = (const float*)d_in[13];
  const float* beta = (const float*)d_in[14];

  char* ws = (char*)d_ws;
  unsigned short* Abf[6];
  for (int i = 0; i < 6; i++) Abf[i] = (unsigned short*)(ws + (size_t)i * 16 * MB);
  unsigned short* WqT = (unsigned short*)(ws + 96 * MB);   // [1024][2048]
  unsigned short* WkT = (unsigned short*)(ws + 100 * MB);
  unsigned short* WvT = (unsigned short*)(ws + 104 * MB);
  unsigned short* WfcT = (unsigned short*)(ws + 108 * MB); // [1024][1024]
  unsigned short* Qb = (unsigned short*)(ws + 110 * MB);   // [64][2048][64]
  unsigned short* Kb = (unsigned short*)(ws + 126 * MB);
  unsigned short* Vtb = (unsigned short*)(ws + 142 * MB);  // [64][64][64][32] tiled
  unsigned short* Ob = (unsigned short*)(ws + 158 * MB);   // [8192][1024]
  float* fcout = (float*)(ws + 16 * MB);  // aliases Abf[1],Abf[2] (dead after proj GEMMs)

  CvtArgs ca;
  for (int i = 0; i < 6; i++) { ca.in[i] = fin[i]; ca.out[i] = Abf[i]; }
  cvt_kernel<<<dim3(1024, 6), 256, 0, stream>>>(ca, 2097152);

  TcvtArgs ta;
  const int wsel[7] = {0, 3, 1, 4, 2, 5, 6};
  unsigned short* wdst[7] = {WqT, WqT, WkT, WkT, WvT, WvT, WfcT};
  for (int i = 0; i < 7; i++) {
    ta.src[i] = Wf[wsel[i]];
    ta.dst[i] = wdst[i];
    ta.stride[i] = (i < 6) ? 2048 : 1024;
    ta.koff[i] = (i < 6) ? ((i & 1) ? 1024 : 0) : 0;
  }
  tcvt_kernel<<<dim3(32, 32, 7), 256, 0, stream>>>(ta);

  G3Args g3;
  g3.A1[0] = Abf[0]; g3.A2[0] = Abf[3]; g3.WT[0] = WqT; g3.out[0] = Qb;
  g3.A1[1] = Abf[1]; g3.A2[1] = Abf[4]; g3.WT[1] = WkT; g3.out[1] = Kb;
  g3.A1[2] = Abf[2]; g3.A2[2] = Abf[5]; g3.WT[2] = WvT; g3.out[2] = Vtb;
  gemm3_kernel<<<1536, 256, 0, stream>>>(g3);

  attn_kernel<<<1024, 256, 0, stream>>>(Qb, Kb, Vtb, Ob);

  gemmfc_kernel<<<512, 256, 0, stream>>>(Ob, WfcT, fin[0], fin[3], fcout);

  ln_kernel<<<8192, 256, 0, stream>>>(fcout, gamma, beta, (float*)d_out);
}